// Round 1
// baseline (373.866 us; speedup 1.0000x reference)
//
#include <hip/hip_runtime.h>
#include <hip/hip_bf16.h>

#define OUTF 12288
#define INF  8192
#define NGRP 128          // K groups (group size 64)
#define MTOT 512          // 4*128

#define BM 128
#define BN 128
#define BK 64
#define NKT (INF / BK)    // 128 K-steps, 1 quant group each

typedef _Float16 h2 __attribute__((ext_vector_type(2)));
typedef _Float16 h8 __attribute__((ext_vector_type(8)));
typedef float    f4 __attribute__((ext_vector_type(4)));

union U2 { unsigned int u; h2 h; };

// ---------------------------------------------------------------------------
// x convert: fp32 -> fp16, written in the SAME per-16-block k-permutation the
// dequant path produces naturally: pair-word q holds (orig q, orig q+8).
// A k-permutation shared by A and B operands cancels inside MFMA.
// ---------------------------------------------------------------------------
__global__ __launch_bounds__(256) void xconvert(const float* __restrict__ x,
                                                _Float16* __restrict__ xh)
{
    int t = blockIdx.x * 256 + threadIdx.x;          // one 16-elem block per thread
    const float4* src = (const float4*)(x + (size_t)t * 16);
    float4 a = src[0];   // k0..3
    float4 b = src[1];   // k4..7
    float4 c = src[2];   // k8..11
    float4 d = src[3];   // k12..15
    U2 o0, o1, o2, o3, o4, o5, o6, o7;
    o0.h = h2{(_Float16)a.x, (_Float16)c.x};
    o1.h = h2{(_Float16)a.y, (_Float16)c.y};
    o2.h = h2{(_Float16)a.z, (_Float16)c.z};
    o3.h = h2{(_Float16)a.w, (_Float16)c.w};
    o4.h = h2{(_Float16)b.x, (_Float16)d.x};
    o5.h = h2{(_Float16)b.y, (_Float16)d.y};
    o6.h = h2{(_Float16)b.z, (_Float16)d.z};
    o7.h = h2{(_Float16)b.w, (_Float16)d.w};
    uint4* dst = (uint4*)(xh + (size_t)t * 16);
    dst[0] = make_uint4(o0.u, o1.u, o2.u, o3.u);
    dst[1] = make_uint4(o4.u, o5.u, o6.u, o7.u);
}

// ---------------------------------------------------------------------------
// Fused dequant + GEMM.  C[m][o] = sum_k x[m][k] * (nib(o,k)*scale + bias)
// BM=128 BN=128 BK=64 (= one group), 4 waves, 4x4 frags of mfma 16x16x32 f16.
// ---------------------------------------------------------------------------
__global__ __launch_bounds__(256, 2) void gql_mfma(
    const _Float16* __restrict__ xh,
    const int*      __restrict__ wp,
    const float*    __restrict__ wsc,
    const float*    __restrict__ wbi,
    float*          __restrict__ out)
{
    __shared__ __align__(16) unsigned char ldsA[2][BM * BK * 2];  // 16 KB each
    __shared__ __align__(16) unsigned char ldsB[2][BN * BK * 2];

    const int tid  = threadIdx.x;
    const int lane = tid & 63;
    const int wv   = tid >> 6;
    const int wr   = wv >> 1;          // wave row 0..1  (64 rows each)
    const int wc   = wv & 1;           // wave col 0..1  (64 cols each)

    const int bm = blockIdx.x & 3;     // 4 M tiles
    const int bn = blockIdx.x >> 2;    // 96 N tiles
    const int m0 = bm * BM;
    const int n0 = bn * BN;

    // ---- A staging: 4 x 16B per thread, pre-swizzled global source so the
    //      linear global_load_lds destination yields a swizzled LDS tile.
    const _Float16* asrc[4];
#pragma unroll
    for (int ia = 0; ia < 4; ++ia) {
        int L    = ia * 4096 + tid * 16;            // linear LDS byte offset
        int row  = L >> 7;
        int ksw  = L & 127;
        int ksrc = ksw ^ ((row & 7) << 4);          // inverse swizzle on source
        asrc[ia] = xh + (size_t)(m0 + row) * INF + (ksrc >> 1);
    }

    // ---- B staging: thread t owns out row (t>>2), 4-word block (t&3); x2 iters
    const int olb = tid >> 2;          // 0..63
    const int blk = tid & 3;
    size_t wpo[2]; int sbo[2]; int bw0[2];
#pragma unroll
    for (int it = 0; it < 2; ++it) {
        int ol  = it * 64 + olb;
        wpo[it] = (size_t)(n0 + ol) * NGRP * 16 + blk * 4;
        sbo[it] = (n0 + ol) * NGRP;
        bw0[it] = ol * 128 + ((blk * 32) ^ ((ol & 7) << 4));   // swizzled LDS byte
    }

    f4 acc[4][4];
#pragma unroll
    for (int i = 0; i < 4; ++i)
#pragma unroll
        for (int j = 0; j < 4; ++j)
            acc[i][j] = f4{0.f, 0.f, 0.f, 0.f};

    uint4 wreg[2]; float sreg[2], breg[2];

    auto loadB = [&](int kt) {
#pragma unroll
        for (int it = 0; it < 2; ++it) {
            wreg[it] = *(const uint4*)(wp + wpo[it] + (size_t)kt * 16);
            sreg[it] = wsc[sbo[it] + kt];
            breg[it] = wbi[sbo[it] + kt];
        }
    };

    auto stageA = [&](int kt, int bufsel) {
#pragma unroll
        for (int ia = 0; ia < 4; ++ia) {
            __builtin_amdgcn_global_load_lds(
                (const __attribute__((address_space(1))) void*)(asrc[ia] + kt * 64),
                (__attribute__((address_space(3))) void*)(&ldsA[bufsel][ia * 4096 + tid * 16]),
                16, 0, 0);
        }
    };

    // packed-fp16 dequant: nibble as fp16 subnormal (n*2^-24), *4096 -> n*2^-12,
    // pk_fma with scale*4096 and bias.  Output pair-word order == xconvert's.
    auto dequant = [&](int bufsel) {
#pragma unroll
        for (int it = 0; it < 2; ++it) {
            _Float16 sh = (_Float16)(sreg[it] * 4096.0f);
            _Float16 bh = (_Float16)breg[it];
            h2 S  = h2{sh, sh};
            h2 Bv = h2{bh, bh};
            h2 K  = h2{(_Float16)4096.0f, (_Float16)4096.0f};
            unsigned int wa[4] = {wreg[it].x, wreg[it].y, wreg[it].z, wreg[it].w};
            unsigned int ow[8];
#pragma unroll
            for (int j = 0; j < 4; ++j) {
                unsigned int w  = wa[j];
                unsigned int t2 = w | (w << 8);
                U2 c02, c13, r02, r13;
                c02.u = t2 & 0x000F000Fu;          // nibbles (i=0, i=2) -> k j, j+8
                c13.u = (t2 >> 4) & 0x000F000Fu;   // nibbles (i=1, i=3) -> k 4+j, 12+j
                r02.h = (c02.h * K) * S + Bv;
                r13.h = (c13.h * K) * S + Bv;
                ow[j]     = r02.u;                 // pair-word q = j
                ow[4 + j] = r13.u;                 // pair-word q = 4+j
            }
            *(uint4*)(&ldsB[bufsel][bw0[it]])      = make_uint4(ow[0], ow[1], ow[2], ow[3]);
            *(uint4*)(&ldsB[bufsel][bw0[it] ^ 16]) = make_uint4(ow[4], ow[5], ow[6], ow[7]);
        }
    };

    auto compute = [&](int bufsel) {
#pragma unroll
        for (int kk = 0; kk < 2; ++kk) {
            h8 af[4], bf[4];
#pragma unroll
            for (int i = 0; i < 4; ++i) {
                int row = wr * 64 + i * 16 + (lane & 15);
                int off = row * 128 + ((kk * 64 + ((lane >> 4) << 4)) ^ ((row & 7) << 4));
                af[i] = *(const h8*)(&ldsA[bufsel][off]);
            }
#pragma unroll
            for (int j = 0; j < 4; ++j) {
                int col = wc * 64 + j * 16 + (lane & 15);
                int off = col * 128 + ((kk * 64 + ((lane >> 4) << 4)) ^ ((col & 7) << 4));
                bf[j] = *(const h8*)(&ldsB[bufsel][off]);
            }
#pragma unroll
            for (int i = 0; i < 4; ++i)
#pragma unroll
                for (int j = 0; j < 4; ++j)
                    acc[i][j] = __builtin_amdgcn_mfma_f32_16x16x32_f16(af[i], bf[j], acc[i][j], 0, 0, 0);
        }
    };

    // ---- prologue
    loadB(0);
    stageA(0, 0);
    dequant(0);                 // compiler inserts the vmcnt wait on wreg
    __syncthreads();

    // ---- main loop: issue next-tile loads, compute current, dequant next
    for (int kt = 0; kt < NKT; ++kt) {
        int cur = kt & 1;
        if (kt + 1 < NKT) {
            loadB(kt + 1);
            stageA(kt + 1, cur ^ 1);
        }
        compute(cur);
        if (kt + 1 < NKT) dequant(cur ^ 1);
        __syncthreads();
    }

    // ---- epilogue: C frag is col=lane&15, row=(lane>>4)*4+r
    const int cr = (lane >> 4) << 2;
    const int cc = lane & 15;
#pragma unroll
    for (int i = 0; i < 4; ++i)
#pragma unroll
        for (int j = 0; j < 4; ++j) {
            int grow = m0 + wr * 64 + i * 16 + cr;
            int gcol = n0 + wc * 64 + j * 16 + cc;
            float* p = out + (size_t)grow * OUTF + gcol;
            p[0 * OUTF] = acc[i][j][0];
            p[1 * OUTF] = acc[i][j][1];
            p[2 * OUTF] = acc[i][j][2];
            p[3 * OUTF] = acc[i][j][3];
        }
}

// ---------------------------------------------------------------------------
extern "C" void kernel_launch(void* const* d_in, const int* in_sizes, int n_in,
                              void* d_out, int out_size, void* d_ws, size_t ws_size,
                              hipStream_t stream)
{
    const float* x  = (const float*)d_in[0];
    const int*   wq = (const int*)d_in[1];
    const float* ws = (const float*)d_in[2];
    const float* wb = (const float*)d_in[3];
    float* o        = (float*)d_out;
    _Float16* xh    = (_Float16*)d_ws;      // 512*8192*2 = 8 MB staging

    xconvert<<<(MTOT * (size_t)INF / 16) / 256, 256, 0, stream>>>(x, xh);
    gql_mfma<<<(MTOT / BM) * (OUTF / BN), 256, 0, stream>>>(xh, wq, ws, wb, o);
}

// Round 2
// 312.210 us; speedup vs baseline: 1.1975x; 1.1975x over previous
//
#include <hip/hip_runtime.h>
#include <hip/hip_bf16.h>

#define OUTF 12288
#define INF  8192
#define MTOT 512

#define BM 128
#define BN 64
#define BK 64
#define NKT 128           // K-steps (= quant groups)

typedef _Float16 h2 __attribute__((ext_vector_type(2)));
typedef _Float16 h8 __attribute__((ext_vector_type(8)));
typedef float    f4 __attribute__((ext_vector_type(4)));

union U2 { unsigned int u; h2 h; };

// ---------------------------------------------------------------------------
// x convert: fp32 -> fp16 in the per-16-block k-permutation the dequant path
// produces (pair-word q holds orig (q, q+8)).  Shared A/B permutation cancels
// inside MFMA.
// ---------------------------------------------------------------------------
__global__ __launch_bounds__(256) void xconvert(const float* __restrict__ x,
                                                _Float16* __restrict__ xh)
{
    int t = blockIdx.x * 256 + threadIdx.x;
    const float4* src = (const float4*)(x + (size_t)t * 16);
    float4 a = src[0];
    float4 b = src[1];
    float4 c = src[2];
    float4 d = src[3];
    U2 o0, o1, o2, o3, o4, o5, o6, o7;
    o0.h = h2{(_Float16)a.x, (_Float16)c.x};
    o1.h = h2{(_Float16)a.y, (_Float16)c.y};
    o2.h = h2{(_Float16)a.z, (_Float16)c.z};
    o3.h = h2{(_Float16)a.w, (_Float16)c.w};
    o4.h = h2{(_Float16)b.x, (_Float16)d.x};
    o5.h = h2{(_Float16)b.y, (_Float16)d.y};
    o6.h = h2{(_Float16)b.z, (_Float16)d.z};
    o7.h = h2{(_Float16)b.w, (_Float16)d.w};
    uint4* dst = (uint4*)(xh + (size_t)t * 16);
    dst[0] = make_uint4(o0.u, o1.u, o2.u, o3.u);
    dst[1] = make_uint4(o4.u, o5.u, o6.u, o7.u);
}

// ---------------------------------------------------------------------------
// Fused dequant + GEMM.  BM=128 BN=64 BK=64 (one group/K-step), 4 waves in a
// 2x2 grid (wave tile 64x32), 48 KB LDS -> 3 blocks/CU, grid 768 = 3/CU.
// Counted-vmcnt raw barriers keep the next w-tile load in flight (depth 2).
// ---------------------------------------------------------------------------
__global__ __launch_bounds__(256, 3) void gql_mfma(
    const _Float16* __restrict__ xh,
    const int*      __restrict__ wp,
    const float*    __restrict__ wsc,
    const float*    __restrict__ wbi,
    float*          __restrict__ out)
{
    __shared__ __align__(16) unsigned char ldsA[2][BM * BK * 2];  // 2 x 16 KB
    __shared__ __align__(16) unsigned char ldsB[2][BN * BK * 2];  // 2 x  8 KB

    const int tid  = threadIdx.x;
    const int lane = tid & 63;
    const int wv   = tid >> 6;
    const int wr   = wv >> 1;          // wave row 0..1 (64 rows)
    const int wc   = wv & 1;           // wave col 0..1 (32 cols)

    // bijective XCD swizzle (768 % 8 == 0): XCD x gets a contiguous bn range
    const int swz = (blockIdx.x & 7) * 96 + (blockIdx.x >> 3);
    const int m0  = (swz & 3) * BM;    // 4 M tiles
    const int n0  = (swz >> 2) * BN;   // 192 N tiles

    // ---- A staging: 4 x 16B per thread via global_load_lds; source is
    //      pre-swizzled so the linear LDS destination lands swizzled.
    const _Float16* asrc[4];
#pragma unroll
    for (int ia = 0; ia < 4; ++ia) {
        int L    = ia * 4096 + tid * 16;            // linear LDS byte
        int row  = L >> 7;
        int ksrc = (L & 127) ^ ((row & 7) << 4);
        asrc[ia] = xh + (size_t)(m0 + row) * INF + (ksrc >> 1);
    }

    // ---- B staging: thread owns out-row tid>>2, 4-word block tid&3 (1 uint4)
    const int brow = tid >> 2;                       // 0..63
    const int bblk = tid & 3;
    const size_t wpo = (size_t)(n0 + brow) * 2048 + bblk * 4;
    const int sco = (n0 + brow) * 128;
    const int bw0 = brow * 128 + ((bblk * 32) ^ ((brow & 7) << 4));

    // ---- fragment LDS byte offsets (constant over the K loop)
    int aoff[2][4], boff[2][2];
#pragma unroll
    for (int kk = 0; kk < 2; ++kk) {
        int kb = kk * 64 + ((lane >> 4) << 4);
#pragma unroll
        for (int i = 0; i < 4; ++i) {
            int row = wr * 64 + i * 16 + (lane & 15);
            aoff[kk][i] = row * 128 + (kb ^ ((row & 7) << 4));
        }
#pragma unroll
        for (int j = 0; j < 2; ++j) {
            int col = wc * 32 + j * 16 + (lane & 15);
            boff[kk][j] = col * 128 + (kb ^ ((col & 7) << 4));
        }
    }

    f4 acc[4][2];
#pragma unroll
    for (int i = 0; i < 4; ++i)
#pragma unroll
        for (int j = 0; j < 2; ++j)
            acc[i][j] = f4{0.f, 0.f, 0.f, 0.f};

    uint4 w0, w1; float s0, s1, b0, b1;

    auto stageA = [&](int kt, int buf) {
#pragma unroll
        for (int ia = 0; ia < 4; ++ia)
            __builtin_amdgcn_global_load_lds(
                (const __attribute__((address_space(1))) void*)(asrc[ia] + kt * 64),
                (__attribute__((address_space(3))) void*)(&ldsA[buf][ia * 4096 + tid * 16]),
                16, 0, 0);
        // pin queue order: stageA must be OLDER than the following reg loads
        __builtin_amdgcn_sched_barrier(0);
    };

    auto loadB = [&](int kt, uint4& w, float& s, float& b) {
        w = *(const uint4*)(wp + wpo + (size_t)kt * 16);   // exactly 3 vmem ops
        s = wsc[sco + kt];
        b = wbi[sco + kt];
    };

    // packed-fp16 dequant: nibble as fp16 subnormal n*2^-24, *4096 twice with
    // scale folded: (c*4096) * (scale*4096) + bias.  Word (b,j): nibbles i=0..3
    // -> k positions b*16 + i*4 + j; pair-word q of block b = (b16+q, b16+q+8).
    auto dequant = [&](uint4 w, float s, float b, int buf) {
        _Float16 sh = (_Float16)(s * 4096.0f);
        _Float16 bh = (_Float16)b;
        h2 S  = h2{sh, sh};
        h2 Bv = h2{bh, bh};
        h2 K  = h2{(_Float16)4096.0f, (_Float16)4096.0f};
        unsigned int wa[4] = {w.x, w.y, w.z, w.w};
        unsigned int ow[8];
#pragma unroll
        for (int j = 0; j < 4; ++j) {
            unsigned int t2 = wa[j] | (wa[j] << 8);
            U2 c02, c13, r02, r13;
            c02.u = t2 & 0x000F000Fu;
            c13.u = (t2 >> 4) & 0x000F000Fu;
            r02.h = (c02.h * K) * S + Bv;
            r13.h = (c13.h * K) * S + Bv;
            ow[j]     = r02.u;
            ow[4 + j] = r13.u;
        }
        *(uint4*)(&ldsB[buf][bw0])      = make_uint4(ow[0], ow[1], ow[2], ow[3]);
        *(uint4*)(&ldsB[buf][bw0 ^ 16]) = make_uint4(ow[4], ow[5], ow[6], ow[7]);
    };

    auto compute = [&](int buf) {
#pragma unroll
        for (int kk = 0; kk < 2; ++kk) {
            h8 af[4], bf[2];
#pragma unroll
            for (int i = 0; i < 4; ++i) af[i] = *(const h8*)(&ldsA[buf][aoff[kk][i]]);
#pragma unroll
            for (int j = 0; j < 2; ++j) bf[j] = *(const h8*)(&ldsB[buf][boff[kk][j]]);
#pragma unroll
            for (int i = 0; i < 4; ++i)
#pragma unroll
                for (int j = 0; j < 2; ++j)
                    acc[i][j] = __builtin_amdgcn_mfma_f32_16x16x32_f16(af[i], bf[j], acc[i][j], 0, 0, 0);
        }
    };

    // counted-vmcnt barrier: drain stageA, keep newest n loads in flight
#define KBAR(n) do { asm volatile("s_waitcnt vmcnt(" #n ") lgkmcnt(0)" ::: "memory"); \
                     __builtin_amdgcn_s_barrier(); } while (0)

    // ---- prologue: stage kt0, preload w for kt0+kt1, dequant kt0
    stageA(0, 0);
    loadB(0, w0, s0, b0);
    loadB(1, w1, s1, b1);
    dequant(w0, s0, b0, 0);
    KBAR(3);                       // keep loadB(1)'s 3 loads in flight

    // ---- main loop (2 K-steps per iteration; w-prefetch distance 2)
    for (int kt = 0; kt < NKT - 2; kt += 2) {
        stageA(kt + 1, 1);
        loadB(kt + 2, w0, s0, b0);
        compute(0);
        dequant(w1, s1, b1, 1);
        KBAR(3);

        stageA(kt + 2, 0);
        loadB(kt + 3, w1, s1, b1);
        compute(1);
        dequant(w0, s0, b0, 0);
        KBAR(3);
    }
    // ---- tail: kt = 126, 127
    stageA(NKT - 1, 1);
    compute(0);
    dequant(w1, s1, b1, 1);
    KBAR(0);
    compute(1);

    // ---- epilogue: C frag col = lane&15, row = (lane>>4)*4 + r
    const int cr = (lane >> 4) << 2;
    const int cc = lane & 15;
#pragma unroll
    for (int i = 0; i < 4; ++i)
#pragma unroll
        for (int j = 0; j < 2; ++j) {
            int grow = m0 + wr * 64 + i * 16 + cr;
            int gcol = n0 + wc * 32 + j * 16 + cc;
            float* p = out + (size_t)grow * OUTF + gcol;
            p[0 * OUTF] = acc[i][j][0];
            p[1 * OUTF] = acc[i][j][1];
            p[2 * OUTF] = acc[i][j][2];
            p[3 * OUTF] = acc[i][j][3];
        }
#undef KBAR
}

// ---------------------------------------------------------------------------
extern "C" void kernel_launch(void* const* d_in, const int* in_sizes, int n_in,
                              void* d_out, int out_size, void* d_ws, size_t ws_size,
                              hipStream_t stream)
{
    const float* x  = (const float*)d_in[0];
    const int*   wq = (const int*)d_in[1];
    const float* ws = (const float*)d_in[2];
    const float* wb = (const float*)d_in[3];
    float* o        = (float*)d_out;
    _Float16* xh    = (_Float16*)d_ws;      // 8 MB staging

    xconvert<<<(MTOT * (size_t)INF / 16) / 256, 256, 0, stream>>>(x, xh);
    gql_mfma<<<(MTOT / BM) * (OUTF / BN), 256, 0, stream>>>(xh, wq, ws, wb, o);
}